// Round 4
// baseline (569.790 us; speedup 1.0000x reference)
//
#include <hip/hip_runtime.h>
#include <hip/hip_bf16.h>
#include <stdint.h>

#define SEQ   2048
#define DIM   4096
#define NH    32
#define NKV   8
#define HD    128
#define NREP  4
#define QKVN  6144   /* 4096 q | 1024 k | 1024 v */
#define KOFF  4096
#define VOFF  5120

typedef __bf16 bf16;
typedef __attribute__((ext_vector_type(8))) __bf16 bf16x8;
typedef __attribute__((ext_vector_type(4))) __bf16 bf16x4;
typedef __attribute__((ext_vector_type(4))) float  f32x4;
typedef __attribute__((address_space(1))) void as1_void;
typedef __attribute__((address_space(3))) void as3_void;

__device__ __forceinline__ void async_copy16(void* lds, const void* g) {
  // LDS dest is wave-uniform base + lane*16; global side may be lane-permuted.
  __builtin_amdgcn_global_load_lds((as1_void*)(void*)g, (as3_void*)lds, 16, 0, 0);
}

__device__ __forceinline__ uint32_t pack2bf(float a, float b) {
  union { bf16 h; uint16_t u; } ca, cb;
  ca.h = (bf16)a; cb.h = (bf16)b;
  return (uint32_t)ca.u | ((uint32_t)cb.u << 16);
}

// ---------------- elementwise fp32 -> bf16 cast (x) ----------------
__global__ __launch_bounds__(256) void cast_x_kernel(const float* __restrict__ src,
                                                     bf16* __restrict__ dst) {
  size_t i = ((size_t)blockIdx.x * 256 + threadIdx.x) * 4;
  const float4 v = *(const float4*)(src + i);
  bf16x4 o;
  o[0] = (bf16)v.x; o[1] = (bf16)v.y; o[2] = (bf16)v.z; o[3] = (bf16)v.w;
  *(bf16x4*)(dst + i) = o;
}

// ---------------- tiled transpose-cast: src fp32 (R x C) -> dst bf16 (C x R) ----------------
// Writes bf16x2 (4 B/lane, 128 B per 32-lane row-group). LDS reads are 2-way (free).
__global__ __launch_bounds__(256) void transpose_cast_kernel(const float* __restrict__ src,
                                                             bf16* __restrict__ dst,
                                                             int R, int C) {
  __shared__ float tile[32][33];
  int c0 = blockIdx.x * 32, r0 = blockIdx.y * 32;
  int tx = threadIdx.x & 31, ty = threadIdx.x >> 5;   // 32 x 8
#pragma unroll
  for (int j = 0; j < 4; ++j)
    tile[ty + j*8][tx] = src[(size_t)(r0 + ty + j*8) * C + c0 + tx];
  __syncthreads();
  int g = threadIdx.x >> 4;       // 0..15  (dst row group)
  int k = threadIdx.x & 15;       // 0..15  (dst col pair)
#pragma unroll
  for (int jj = 0; jj < 2; ++jj) {
    int X  = g + jj*16;           // src col = dst row
    int Y0 = k*2;                 // src row pair
    uint32_t pv = pack2bf(tile[Y0][X], tile[Y0+1][X]);
    *(uint32_t*)&dst[(size_t)(c0 + X) * R + r0 + Y0] = pv;
  }
}

// ---------------- m97-style GEMM: C(MxN) = A(MxK) * Bt(NxK)^T, bf16 in, fp32/bf16 out --------
template<int OUT_F32>
__global__ __launch_bounds__(256) void gemm_bt_kernel(const bf16* __restrict__ A,
                                                      const bf16* __restrict__ Bt,
                                                      void* __restrict__ Cout,
                                                      int M, int N, int K) {
  __shared__ __align__(16) bf16 As[128*32];
  __shared__ __align__(16) bf16 Bs[128*32];
  const int tid = threadIdx.x;
  const int w = tid >> 6, lane = tid & 63;
  const int lane16 = lane & 15, quad = lane >> 4;
  const int wr = w >> 1, wc = w & 1;           // 2x2 wave grid, each wave 64x64
  const int bm = blockIdx.y * 128, bn = blockIdx.x * 128;
  const bf16* a0 = A  + (size_t)bm * K;
  const bf16* b0 = Bt + (size_t)bn * K;
  f32x4 acc[4][4] = {};
  for (int k0 = 0; k0 < K; k0 += 32) {
    __syncthreads();                            // prev iter ds_reads done before overwrite
#pragma unroll
    for (int i = 0; i < 2; ++i) {
      int c = tid + i * 256;                    // 512 chunks of 16B: row=c>>2, sub=c&3
      async_copy16(&As[c*8], a0 + (size_t)(c >> 2) * K + k0 + (c & 3) * 8);
      async_copy16(&Bs[c*8], b0 + (size_t)(c >> 2) * K + k0 + (c & 3) * 8);
    }
    __syncthreads();                            // barrier drains vmcnt
    bf16x8 af[4];
#pragma unroll
    for (int i = 0; i < 4; ++i)
      af[i] = *(const bf16x8*)&As[(wr*64 + i*16 + lane16)*32 + quad*8];
#pragma unroll
    for (int j = 0; j < 4; ++j) {
      bf16x8 bfrag = *(const bf16x8*)&Bs[(wc*64 + j*16 + lane16)*32 + quad*8];
#pragma unroll
      for (int i = 0; i < 4; ++i)
        acc[i][j] = __builtin_amdgcn_mfma_f32_16x16x32_bf16(af[i], bfrag, acc[i][j], 0, 0, 0);
    }
  }
#pragma unroll
  for (int i = 0; i < 4; ++i)
#pragma unroll
    for (int j = 0; j < 4; ++j)
#pragma unroll
      for (int r = 0; r < 4; ++r) {
        size_t row = (size_t)bm + wr*64 + i*16 + quad*4 + r;   // C/D: row=quad*4+reg
        size_t col = (size_t)bn + wc*64 + j*16 + lane16;       //      col=lane&15
        float v = acc[i][j][r];
        if (OUT_F32) ((float*)Cout)[row * N + col] = v;
        else         ((bf16*)Cout)[row * N + col] = (bf16)v;
      }
}

// ---------------- RoPE on q (32 heads) and k (8 heads), in place on qkv ----------------
__global__ __launch_bounds__(256) void rope_kernel(bf16* __restrict__ qkv,
                                                   const float* __restrict__ fr) {
  int idx = blockIdx.x * 256 + threadIdx.x;     // 2048*40*64 threads
  int p  = idx & 63;
  int hh = (idx >> 6) % 40;
  int t  = (idx >> 6) / 40;
  int col = (hh < NH) ? (hh * HD + 2*p) : (KOFF + (hh - NH) * HD + 2*p);
  float c = fr[((size_t)t*64 + p)*2 + 0];
  float d = fr[((size_t)t*64 + p)*2 + 1];
  bf16* ptr = qkv + (size_t)t * QKVN + col;
  float a = (float)ptr[0], b = (float)ptr[1];
  ptr[0] = (bf16)(a*c - b*d);
  ptr[1] = (bf16)(a*d + b*c);
}

// ---------------- transpose v slice of qkv -> vt[kv][d][t] ----------------
__global__ __launch_bounds__(256) void transpose_v_kernel(const bf16* __restrict__ qkv,
                                                          bf16* __restrict__ vt) {
  __shared__ bf16 tile[32][33];
  int tt = blockIdx.x * 32;
  int dd = blockIdx.y * 32;
  int kv = blockIdx.z;
  int tx = threadIdx.x & 31, ty = threadIdx.x >> 5;
  const bf16* src = qkv + VOFF + kv * HD;
#pragma unroll
  for (int j = 0; j < 4; ++j)
    tile[ty + j*8][tx] = src[(size_t)(tt + ty + j*8) * QKVN + dd + tx];
  __syncthreads();
  bf16* dst = vt + ((size_t)kv * HD + dd) * SEQ + tt;
#pragma unroll
  for (int j = 0; j < 4; ++j)
    dst[(size_t)(ty + j*8) * SEQ + tx] = tile[tx][ty + j*8];
}

// ---------------- flash attention v3 ----------------
// One (head, 64-row Q tile) per block; 4 waves each own 16 q columns.
// Q A-fragments live in REGISTERS (no Qs LDS). KV tile = 96 (1.5x MFMA per
// barrier vs 64), LDS = 24+24 KB -> 3 blocks/CU. Transposed softmax (S^T=K Q^T,
// scalar-per-lane state), alpha/l re-mapped to C-rows via __shfl(., quad*4+r).
// Causal mask applied unconditionally (96 doesn't align to 64-q diagonal); OOB
// kv rows (< 2112) read adjacent workspace (finite) and are masked to exp->0.
__global__ __launch_bounds__(256, 3) void flash_attn_kernel(const bf16* __restrict__ qkv,
                                                            const bf16* __restrict__ vt,
                                                            bf16* __restrict__ out) {
  __shared__ __align__(16) bf16 Ks[4*96*32];    // [kk=4][kvrow=96][32]   24 KB
  __shared__ __align__(16) bf16 Vts[3*128*32];  // [kk2=3][d=128][32kv]   24 KB
  const int b  = blockIdx.x;                    // 1D, qt-descending for balance
  const int qt = 31 - (b >> 5);
  const int h  = b & 31;
  const int kvh = h >> 2;                       // NREP = 4
  const int tid = threadIdx.x;
  const int w = tid >> 6, lane = tid & 63;
  const int lane16 = lane & 15, quad = lane >> 4;
  const float scale = 0.08838834764831845f;     // 1/sqrt(128)
  const int qglob = qt*64 + w*16 + lane16;      // this lane's q column

  // Q A-fragment in registers: lane needs Q[qglob][kk*32 + quad*8 .. +8]
  const bf16* qrow = qkv + (size_t)qglob * QKVN + h * HD + quad*8;
  bf16x8 qreg[4];
#pragma unroll
  for (int kk = 0; kk < 4; ++kk)
    qreg[kk] = *(const bf16x8*)(qrow + kk*32);

  f32x4 acc_o[8] = {};                          // [jd][reg]: row q=quad*4+reg, col d=jd*16+lane16
  float m_s = -3e38f, l_s = 0.f;                // scalar per lane (column q)

  const bf16* kbase0 = qkv + KOFF + kvh * HD;
  const bf16* vbase0 = vt + (size_t)kvh * HD * SEQ;

  const int L = (qt*64 + 159) / 96;             // ceil((qt+1)*64 / 96) kv tiles
  for (int jj = 0; jj < L; ++jj) {
    const int kv0 = jj * 96;
    __syncthreads();                            // prior iter's ds_reads done before restage
#pragma unroll
    for (int i = 0; i < 6; ++i) {               // 1536 chunks each for K and Vt
      int c = tid + i * 256;
      {
        int kk = c / 384, rem = c - kk*384;     // K: [kk][kvrow][32]
        async_copy16(&Ks[c*8], kbase0 + (size_t)(kv0 + (rem >> 2)) * QKVN + kk*32 + (rem & 3) * 8);
      }
      {
        int kk2 = c >> 9, cp = c & 511;         // Vt: [kk2][d][32kv]
        async_copy16(&Vts[c*8], vbase0 + (size_t)(cp >> 2) * SEQ + kv0 + kk2*32 + (cp & 3) * 8);
      }
    }
    __syncthreads();                            // drains staging

    // S^T = K Q^T : A=K rows (m=kv), B=Q rows (n=q). acc row=kv local, col=q.
    f32x4 accT[6] = {};
#pragma unroll
    for (int kk = 0; kk < 4; ++kk)
#pragma unroll
      for (int jn = 0; jn < 6; ++jn) {
        bf16x8 kf = *(const bf16x8*)&Ks[(kk*96 + jn*16 + lane16)*32 + quad*8];
        accT[jn] = __builtin_amdgcn_mfma_f32_16x16x32_bf16(kf, qreg[kk], accT[jn], 0, 0, 0);
      }

    // scale + unconditional causal mask (kv > q). lane's kv: kv0 + jn*16 + quad*4 + r
    float s[6][4];
#pragma unroll
    for (int jn = 0; jn < 6; ++jn)
#pragma unroll
      for (int r = 0; r < 4; ++r) {
        float v = accT[jn][r] * scale;
        if ((kv0 + jn*16 + quad*4 + r) > qglob) v = -3e38f;
        s[jn][r] = v;
      }

    // online softmax (transposed): column stats replicated across quads
    float mt = s[0][0];
#pragma unroll
    for (int jn = 0; jn < 6; ++jn)
#pragma unroll
      for (int r = 0; r < 4; ++r) mt = fmaxf(mt, s[jn][r]);
    mt = fmaxf(mt, __shfl_xor(mt, 16));
    mt = fmaxf(mt, __shfl_xor(mt, 32));
    float mnew = fmaxf(m_s, mt);
    float alpha = __expf(m_s - mnew);
    m_s = mnew;
    float rs = 0.f;
#pragma unroll
    for (int jn = 0; jn < 6; ++jn)
#pragma unroll
      for (int r = 0; r < 4; ++r) {
        float p = __expf(s[jn][r] - mnew);
        s[jn][r] = p;
        rs += p;
      }
    rs += __shfl_xor(rs, 16);
    rs += __shfl_xor(rs, 32);
    l_s = l_s * alpha + rs;

    // acc_o rows are q = quad*4+r: pull the matching column's alpha from lane quad*4+r
    float alpha_row[4];
#pragma unroll
    for (int r = 0; r < 4; ++r)
      alpha_row[r] = __shfl(alpha, quad*4 + r);
#pragma unroll
    for (int jd = 0; jd < 8; ++jd)
#pragma unroll
      for (int r = 0; r < 4; ++r) acc_o[jd][r] *= alpha_row[r];

    // pack P columns: pk[jn] = bf16x4 of s[jn][0..3] as 2 u32
    uint32_t pk[6][2];
#pragma unroll
    for (int jn = 0; jn < 6; ++jn) {
      pk[jn][0] = pack2bf(s[jn][0], s[jn][1]);
      pk[jn][1] = pack2bf(s[jn][2], s[jn][3]);
    }

    // P(C-layout, transposed) -> A-frag via cross-quad shuffles at fixed lane16.
    // dest (quad,lane16) elem jjj: kv = kk2*32 + quad*8 + jjj ->
    //   src jn = kk2*2 + (quad>>1), src quad_s = (quad&1)*2 + (jjj>>2), r = jjj&3
    const int src0 = (quad & 1) * 32 + lane16;
    const int src1 = src0 + 16;
    const bool hi = quad >= 2;
#pragma unroll
    for (int kk2 = 0; kk2 < 3; ++kk2) {
      uint32_t v0l = __shfl(pk[2*kk2][0],   src0), v0h = __shfl(pk[2*kk2][1],   src0);
      uint32_t v1l = __shfl(pk[2*kk2][0],   src1), v1h = __shfl(pk[2*kk2][1],   src1);
      uint32_t w0l = __shfl(pk[2*kk2+1][0], src0), w0h = __shfl(pk[2*kk2+1][1], src0);
      uint32_t w1l = __shfl(pk[2*kk2+1][0], src1), w1h = __shfl(pk[2*kk2+1][1], src1);
      union { uint32_t u[4]; bf16x8 v; } af;
      af.u[0] = hi ? w0l : v0l;                 // jjj 0,1
      af.u[1] = hi ? w0h : v0h;                 // jjj 2,3
      af.u[2] = hi ? w1l : v1l;                 // jjj 4,5
      af.u[3] = hi ? w1h : v1h;                 // jjj 6,7
#pragma unroll
      for (int jd = 0; jd < 8; ++jd) {
        bf16x8 vf = *(const bf16x8*)&Vts[(kk2*128 + jd*16 + lane16)*32 + quad*8];
        acc_o[jd] = __builtin_amdgcn_mfma_f32_16x16x32_bf16(af.v, vf, acc_o[jd], 0, 0, 0);
      }
    }
  }

  // final normalize: l for row q=quad*4+r lives (replicated) at lane quad*4+r
  const float inv_l = 1.f / l_s;
  float linv[4];
#pragma unroll
  for (int r = 0; r < 4; ++r)
    linv[r] = __shfl(inv_l, quad*4 + r);

  bf16* obase = out + (size_t)(qt*64 + w*16) * DIM + h * HD;
#pragma unroll
  for (int jd = 0; jd < 8; ++jd)
#pragma unroll
    for (int r = 0; r < 4; ++r)
      obase[(size_t)(quad*4 + r) * DIM + jd*16 + lane16] = (bf16)(acc_o[jd][r] * linv[r]);
}

extern "C" void kernel_launch(void* const* d_in, const int* in_sizes, int n_in,
                              void* d_out, int out_size, void* d_ws, size_t ws_size,
                              hipStream_t stream) {
  const float* x  = (const float*)d_in[0];
  // d_in[1] = cache_kv: dead (start_pos=0, L=SEQ -> keys/values == xk/xv)
  const float* fr = (const float*)d_in[2];
  const float* wq = (const float*)d_in[3];
  const float* wk = (const float*)d_in[4];
  const float* wv = (const float*)d_in[5];
  const float* wo = (const float*)d_in[6];
  // d_in[7] = start_pos = 0
  float* out = (float*)d_out;

  char* ws = (char*)d_ws;
  bf16* xb     = (bf16*)(ws);                    // 2048x4096          16,777,216 B
  bf16* wqkv_t = (bf16*)(ws + 16777216);         // 6144x4096 (N,K)   50,331,648 B
  bf16* wo_t   = (bf16*)(ws + 67108864);         // 4096x4096 (N,K)   33,554,432 B
  bf16* qkv    = (bf16*)(ws + 100663296);        // 2048x6144         25,165,824 B
  bf16* vt     = (bf16*)(ws + 125829120);        // 8x128x2048         4,194,304 B
  bf16* attn   = (bf16*)(ws + 130023424);        // 2048x4096         16,777,216 B
  (void)ws_size; (void)in_sizes; (void)n_in; (void)out_size;

  cast_x_kernel<<<8192, 256, 0, stream>>>(x, xb);
  transpose_cast_kernel<<<dim3(128,128), 256, 0, stream>>>(wq, wqkv_t, DIM, DIM);
  transpose_cast_kernel<<<dim3(32,128),  256, 0, stream>>>(wk, wqkv_t + (size_t)4096*4096, DIM, 1024);
  transpose_cast_kernel<<<dim3(32,128),  256, 0, stream>>>(wv, wqkv_t + (size_t)5120*4096, DIM, 1024);
  transpose_cast_kernel<<<dim3(128,128), 256, 0, stream>>>(wo, wo_t, DIM, DIM);

  gemm_bt_kernel<0><<<dim3(48,16), 256, 0, stream>>>(xb, wqkv_t, qkv, SEQ, QKVN, DIM);
  rope_kernel<<<20480, 256, 0, stream>>>(qkv, fr);
  transpose_v_kernel<<<dim3(64,4,8), 256, 0, stream>>>(qkv, vt);
  flash_attn_kernel<<<1024, 256, 0, stream>>>(qkv, vt, attn);
  gemm_bt_kernel<1><<<dim3(32,16), 256, 0, stream>>>(attn, wo_t, out, SEQ, DIM, DIM);
}

// Round 5
// 551.583 us; speedup vs baseline: 1.0330x; 1.0330x over previous
//
#include <hip/hip_runtime.h>
#include <hip/hip_bf16.h>
#include <stdint.h>

#define SEQ   2048
#define DIM   4096
#define NH    32
#define NKV   8
#define HD    128
#define NREP  4
#define QKVN  6144   /* 4096 q | 1024 k | 1024 v */
#define KOFF  4096
#define VOFF  5120

typedef __bf16 bf16;
typedef __attribute__((ext_vector_type(8))) __bf16 bf16x8;
typedef __attribute__((ext_vector_type(4))) __bf16 bf16x4;
typedef __attribute__((ext_vector_type(4))) float  f32x4;
typedef __attribute__((address_space(1))) void as1_void;
typedef __attribute__((address_space(3))) void as3_void;

__device__ __forceinline__ void async_copy16(void* lds, const void* g) {
  // LDS dest is wave-uniform base + lane*16; global side may be lane-permuted.
  __builtin_amdgcn_global_load_lds((as1_void*)(void*)g, (as3_void*)lds, 16, 0, 0);
}

__device__ __forceinline__ uint32_t pack2bf(float a, float b) {
  union { bf16 h; uint16_t u; } ca, cb;
  ca.h = (bf16)a; cb.h = (bf16)b;
  return (uint32_t)ca.u | ((uint32_t)cb.u << 16);
}

// ---------------- elementwise fp32 -> bf16 cast (x) ----------------
__global__ __launch_bounds__(256) void cast_x_kernel(const float* __restrict__ src,
                                                     bf16* __restrict__ dst) {
  size_t i = ((size_t)blockIdx.x * 256 + threadIdx.x) * 4;
  const float4 v = *(const float4*)(src + i);
  bf16x4 o;
  o[0] = (bf16)v.x; o[1] = (bf16)v.y; o[2] = (bf16)v.z; o[3] = (bf16)v.w;
  *(bf16x4*)(dst + i) = o;
}

// ---------------- tiled transpose-cast v2: 64x64, float4 loads, bf16x4 stores ----------------
// src fp32 (R x C) -> dst bf16 (C x R). LDS patterns verified 2-way (free) both directions.
__global__ __launch_bounds__(256) void transpose_cast_kernel(const float* __restrict__ src,
                                                             bf16* __restrict__ dst,
                                                             int R, int C) {
  __shared__ float tile[64][65];
  const int c0 = blockIdx.x * 64, r0 = blockIdx.y * 64;
  const int tx = threadIdx.x & 15, ty = threadIdx.x >> 4;   // 16 x 16
#pragma unroll
  for (int p = 0; p < 4; ++p) {
    float4 v = *(const float4*)&src[(size_t)(r0 + ty + p*16) * C + c0 + tx*4];
    tile[ty + p*16][tx*4+0] = v.x;
    tile[ty + p*16][tx*4+1] = v.y;
    tile[ty + p*16][tx*4+2] = v.z;
    tile[ty + p*16][tx*4+3] = v.w;
  }
  __syncthreads();
  const int k = threadIdx.x & 15;   // dst col quad (Y0 = 4k)
  const int g = threadIdx.x >> 4;   // dst row group
#pragma unroll
  for (int p = 0; p < 4; ++p) {
    int X = g + 16*p;               // src col = dst row
    bf16x4 o;
    o[0] = (bf16)tile[4*k+0][X];
    o[1] = (bf16)tile[4*k+1][X];
    o[2] = (bf16)tile[4*k+2][X];
    o[3] = (bf16)tile[4*k+3][X];
    *(bf16x4*)&dst[(size_t)(c0 + X) * R + r0 + 4*k] = o;
  }
}

// ---------------- GEMM v2: BK=64, C(MxN) = A(MxK) * Bt(NxK)^T ----------------
// LDS panelized [kk=2][row=128][32] (row stride 64B, conflict-free). 32 KB total,
// 2x MFMA per barrier vs BK=32. Optional fused RoPE epilogue (cols < 5120):
// feature pairs (2p,2p+1) sit in adjacent lane16 lanes -> shfl_xor(1) + 2 FMA.
template<int OUT_F32, int ROPE>
__global__ __launch_bounds__(256) void gemm_bt_kernel(const bf16* __restrict__ A,
                                                      const bf16* __restrict__ Bt,
                                                      void* __restrict__ Cout,
                                                      int M, int N, int K,
                                                      const float* __restrict__ fr) {
  __shared__ __align__(16) bf16 As[2*128*32];
  __shared__ __align__(16) bf16 Bs[2*128*32];
  const int tid = threadIdx.x;
  const int w = tid >> 6, lane = tid & 63;
  const int lane16 = lane & 15, quad = lane >> 4;
  const int wr = w >> 1, wc = w & 1;           // 2x2 wave grid, each wave 64x64
  const int bm = blockIdx.y * 128, bn = blockIdx.x * 128;
  const bf16* a0 = A  + (size_t)bm * K;
  const bf16* b0 = Bt + (size_t)bn * K;
  f32x4 acc[4][4] = {};
  for (int k0 = 0; k0 < K; k0 += 64) {
    __syncthreads();                            // prev iter ds_reads done before overwrite
#pragma unroll
    for (int i = 0; i < 4; ++i) {
      int c = tid + i * 256;                    // 1024 chunks: kk=c>>9, row=(c&511)>>2, sub=c&3
      int kk = c >> 9, rem = c & 511;
      async_copy16(&As[c*8], a0 + (size_t)(rem >> 2) * K + k0 + kk*32 + (rem & 3) * 8);
      async_copy16(&Bs[c*8], b0 + (size_t)(rem >> 2) * K + k0 + kk*32 + (rem & 3) * 8);
    }
    __syncthreads();                            // barrier drains vmcnt
#pragma unroll
    for (int kk = 0; kk < 2; ++kk) {
      bf16x8 af[4];
#pragma unroll
      for (int i = 0; i < 4; ++i)
        af[i] = *(const bf16x8*)&As[kk*4096 + (wr*64 + i*16 + lane16)*32 + quad*8];
#pragma unroll
      for (int j = 0; j < 4; ++j) {
        bf16x8 bfrag = *(const bf16x8*)&Bs[kk*4096 + (wc*64 + j*16 + lane16)*32 + quad*8];
#pragma unroll
        for (int i = 0; i < 4; ++i)
          acc[i][j] = __builtin_amdgcn_mfma_f32_16x16x32_bf16(af[i], bfrag, acc[i][j], 0, 0, 0);
      }
    }
  }
#pragma unroll
  for (int i = 0; i < 4; ++i)
#pragma unroll
    for (int j = 0; j < 4; ++j) {
      const bool do_rope = ROPE && (bn + wc*64 + j*16) < 5120;   // wave-uniform per j
      const int p2 = (bn + wc*64 + j*16 + lane16) & 126;         // 2*p within head
#pragma unroll
      for (int r = 0; r < 4; ++r) {
        size_t row = (size_t)bm + wr*64 + i*16 + quad*4 + r;     // C/D: row=quad*4+reg
        size_t col = (size_t)bn + wc*64 + j*16 + lane16;         //      col=lane&15
        float v = acc[i][j][r];
        if (ROPE) {
          float vp = __shfl_xor(v, 1);                           // partner feature value
          if (do_rope) {
            float2 cd = *(const float2*)&fr[row*128 + p2];       // cos,sin for (t,p)
            v = (lane16 & 1) ? (vp*cd.y + v*cd.x) : (v*cd.x - vp*cd.y);
          }
        }
        if (OUT_F32) ((float*)Cout)[row * N + col] = v;
        else         ((bf16*)Cout)[row * N + col] = (bf16)v;
      }
    }
}

// ---------------- transpose v slice of qkv -> vt[kv][d][t] ----------------
__global__ __launch_bounds__(256) void transpose_v_kernel(const bf16* __restrict__ qkv,
                                                          bf16* __restrict__ vt) {
  __shared__ bf16 tile[32][33];
  int tt = blockIdx.x * 32;
  int dd = blockIdx.y * 32;
  int kv = blockIdx.z;
  int tx = threadIdx.x & 31, ty = threadIdx.x >> 5;
  const bf16* src = qkv + VOFF + kv * HD;
#pragma unroll
  for (int j = 0; j < 4; ++j)
    tile[ty + j*8][tx] = src[(size_t)(tt + ty + j*8) * QKVN + dd + tx];
  __syncthreads();
  bf16* dst = vt + ((size_t)kv * HD + dd) * SEQ + tt;
#pragma unroll
  for (int j = 0; j < 4; ++j)
    dst[(size_t)(ty + j*8) * SEQ + tx] = tile[tx][ty + j*8];
}

// ---------------- flash attention v3 (unchanged from round 4) ----------------
__global__ __launch_bounds__(256, 3) void flash_attn_kernel(const bf16* __restrict__ qkv,
                                                            const bf16* __restrict__ vt,
                                                            bf16* __restrict__ out) {
  __shared__ __align__(16) bf16 Ks[4*96*32];    // [kk=4][kvrow=96][32]   24 KB
  __shared__ __align__(16) bf16 Vts[3*128*32];  // [kk2=3][d=128][32kv]   24 KB
  const int b  = blockIdx.x;                    // 1D, qt-descending for balance
  const int qt = 31 - (b >> 5);
  const int h  = b & 31;
  const int kvh = h >> 2;                       // NREP = 4
  const int tid = threadIdx.x;
  const int w = tid >> 6, lane = tid & 63;
  const int lane16 = lane & 15, quad = lane >> 4;
  const float scale = 0.08838834764831845f;     // 1/sqrt(128)
  const int qglob = qt*64 + w*16 + lane16;      // this lane's q column

  // Q A-fragment in registers: lane needs Q[qglob][kk*32 + quad*8 .. +8]
  const bf16* qrow = qkv + (size_t)qglob * QKVN + h * HD + quad*8;
  bf16x8 qreg[4];
#pragma unroll
  for (int kk = 0; kk < 4; ++kk)
    qreg[kk] = *(const bf16x8*)(qrow + kk*32);

  f32x4 acc_o[8] = {};                          // [jd][reg]: row q=quad*4+reg, col d=jd*16+lane16
  float m_s = -3e38f, l_s = 0.f;                // scalar per lane (column q)

  const bf16* kbase0 = qkv + KOFF + kvh * HD;
  const bf16* vbase0 = vt + (size_t)kvh * HD * SEQ;

  const int L = (qt*64 + 159) / 96;             // ceil((qt+1)*64 / 96) kv tiles
  for (int jj = 0; jj < L; ++jj) {
    const int kv0 = jj * 96;
    __syncthreads();                            // prior iter's ds_reads done before restage
#pragma unroll
    for (int i = 0; i < 6; ++i) {               // 1536 chunks each for K and Vt
      int c = tid + i * 256;
      {
        int kk = c / 384, rem = c - kk*384;     // K: [kk][kvrow][32]
        async_copy16(&Ks[c*8], kbase0 + (size_t)(kv0 + (rem >> 2)) * QKVN + kk*32 + (rem & 3) * 8);
      }
      {
        int kk2 = c >> 9, cp = c & 511;         // Vt: [kk2][d][32kv]
        async_copy16(&Vts[c*8], vbase0 + (size_t)(cp >> 2) * SEQ + kv0 + kk2*32 + (cp & 3) * 8);
      }
    }
    __syncthreads();                            // drains staging

    // S^T = K Q^T : A=K rows (m=kv), B=Q rows (n=q). acc row=kv local, col=q.
    f32x4 accT[6] = {};
#pragma unroll
    for (int kk = 0; kk < 4; ++kk)
#pragma unroll
      for (int jn = 0; jn < 6; ++jn) {
        bf16x8 kf = *(const bf16x8*)&Ks[(kk*96 + jn*16 + lane16)*32 + quad*8];
        accT[jn] = __builtin_amdgcn_mfma_f32_16x16x32_bf16(kf, qreg[kk], accT[jn], 0, 0, 0);
      }

    // scale + unconditional causal mask (kv > q). lane's kv: kv0 + jn*16 + quad*4 + r
    float s[6][4];
#pragma unroll
    for (int jn = 0; jn < 6; ++jn)
#pragma unroll
      for (int r = 0; r < 4; ++r) {
        float v = accT[jn][r] * scale;
        if ((kv0 + jn*16 + quad*4 + r) > qglob) v = -3e38f;
        s[jn][r] = v;
      }

    // online softmax (transposed): column stats replicated across quads
    float mt = s[0][0];
#pragma unroll
    for (int jn = 0; jn < 6; ++jn)
#pragma unroll
      for (int r = 0; r < 4; ++r) mt = fmaxf(mt, s[jn][r]);
    mt = fmaxf(mt, __shfl_xor(mt, 16));
    mt = fmaxf(mt, __shfl_xor(mt, 32));
    float mnew = fmaxf(m_s, mt);
    float alpha = __expf(m_s - mnew);
    m_s = mnew;
    float rs = 0.f;
#pragma unroll
    for (int jn = 0; jn < 6; ++jn)
#pragma unroll
      for (int r = 0; r < 4; ++r) {
        float p = __expf(s[jn][r] - mnew);
        s[jn][r] = p;
        rs += p;
      }
    rs += __shfl_xor(rs, 16);
    rs += __shfl_xor(rs, 32);
    l_s = l_s * alpha + rs;

    // acc_o rows are q = quad*4+r: pull the matching column's alpha from lane quad*4+r
    float alpha_row[4];
#pragma unroll
    for (int r = 0; r < 4; ++r)
      alpha_row[r] = __shfl(alpha, quad*4 + r);
#pragma unroll
    for (int jd = 0; jd < 8; ++jd)
#pragma unroll
      for (int r = 0; r < 4; ++r) acc_o[jd][r] *= alpha_row[r];

    // pack P columns: pk[jn] = bf16x4 of s[jn][0..3] as 2 u32
    uint32_t pk[6][2];
#pragma unroll
    for (int jn = 0; jn < 6; ++jn) {
      pk[jn][0] = pack2bf(s[jn][0], s[jn][1]);
      pk[jn][1] = pack2bf(s[jn][2], s[jn][3]);
    }

    // P(C-layout, transposed) -> A-frag via cross-quad shuffles at fixed lane16.
    const int src0 = (quad & 1) * 32 + lane16;
    const int src1 = src0 + 16;
    const bool hi = quad >= 2;
#pragma unroll
    for (int kk2 = 0; kk2 < 3; ++kk2) {
      uint32_t v0l = __shfl(pk[2*kk2][0],   src0), v0h = __shfl(pk[2*kk2][1],   src0);
      uint32_t v1l = __shfl(pk[2*kk2][0],   src1), v1h = __shfl(pk[2*kk2][1],   src1);
      uint32_t w0l = __shfl(pk[2*kk2+1][0], src0), w0h = __shfl(pk[2*kk2+1][1], src0);
      uint32_t w1l = __shfl(pk[2*kk2+1][0], src1), w1h = __shfl(pk[2*kk2+1][1], src1);
      union { uint32_t u[4]; bf16x8 v; } af;
      af.u[0] = hi ? w0l : v0l;                 // jjj 0,1
      af.u[1] = hi ? w0h : v0h;                 // jjj 2,3
      af.u[2] = hi ? w1l : v1l;                 // jjj 4,5
      af.u[3] = hi ? w1h : v1h;                 // jjj 6,7
#pragma unroll
      for (int jd = 0; jd < 8; ++jd) {
        bf16x8 vf = *(const bf16x8*)&Vts[(kk2*128 + jd*16 + lane16)*32 + quad*8];
        acc_o[jd] = __builtin_amdgcn_mfma_f32_16x16x32_bf16(af.v, vf, acc_o[jd], 0, 0, 0);
      }
    }
  }

  // final normalize: l for row q=quad*4+r lives (replicated) at lane quad*4+r
  const float inv_l = 1.f / l_s;
  float linv[4];
#pragma unroll
  for (int r = 0; r < 4; ++r)
    linv[r] = __shfl(inv_l, quad*4 + r);

  bf16* obase = out + (size_t)(qt*64 + w*16) * DIM + h * HD;
#pragma unroll
  for (int jd = 0; jd < 8; ++jd)
#pragma unroll
    for (int r = 0; r < 4; ++r)
      obase[(size_t)(quad*4 + r) * DIM + jd*16 + lane16] = (bf16)(acc_o[jd][r] * linv[r]);
}

extern "C" void kernel_launch(void* const* d_in, const int* in_sizes, int n_in,
                              void* d_out, int out_size, void* d_ws, size_t ws_size,
                              hipStream_t stream) {
  const float* x  = (const float*)d_in[0];
  // d_in[1] = cache_kv: dead (start_pos=0, L=SEQ -> keys/values == xk/xv)
  const float* fr = (const float*)d_in[2];
  const float* wq = (const float*)d_in[3];
  const float* wk = (const float*)d_in[4];
  const float* wv = (const float*)d_in[5];
  const float* wo = (const float*)d_in[6];
  // d_in[7] = start_pos = 0
  float* out = (float*)d_out;

  char* ws = (char*)d_ws;
  bf16* xb     = (bf16*)(ws);                    // 2048x4096          16,777,216 B
  bf16* wqkv_t = (bf16*)(ws + 16777216);         // 6144x4096 (N,K)   50,331,648 B
  bf16* wo_t   = (bf16*)(ws + 67108864);         // 4096x4096 (N,K)   33,554,432 B
  bf16* qkv    = (bf16*)(ws + 100663296);        // 2048x6144         25,165,824 B
  bf16* vt     = (bf16*)(ws + 125829120);        // 8x128x2048         4,194,304 B
  bf16* attn   = (bf16*)(ws + 130023424);        // 2048x4096         16,777,216 B
  (void)ws_size; (void)in_sizes; (void)n_in; (void)out_size;

  cast_x_kernel<<<8192, 256, 0, stream>>>(x, xb);
  transpose_cast_kernel<<<dim3(64,64), 256, 0, stream>>>(wq, wqkv_t, DIM, DIM);
  transpose_cast_kernel<<<dim3(16,64), 256, 0, stream>>>(wk, wqkv_t + (size_t)4096*4096, DIM, 1024);
  transpose_cast_kernel<<<dim3(16,64), 256, 0, stream>>>(wv, wqkv_t + (size_t)5120*4096, DIM, 1024);
  transpose_cast_kernel<<<dim3(64,64), 256, 0, stream>>>(wo, wo_t, DIM, DIM);

  gemm_bt_kernel<0,1><<<dim3(48,16), 256, 0, stream>>>(xb, wqkv_t, qkv, SEQ, QKVN, DIM, fr);
  transpose_v_kernel<<<dim3(64,4,8), 256, 0, stream>>>(qkv, vt);
  flash_attn_kernel<<<1024, 256, 0, stream>>>(qkv, vt, attn);
  gemm_bt_kernel<1,0><<<dim3(32,16), 256, 0, stream>>>(attn, wo_t, out, SEQ, DIM, DIM, nullptr);
}